// Round 1
// baseline (74.412 us; speedup 1.0000x reference)
//
#include <hip/hip_runtime.h>
#include <math.h>

#define EPSF 1e-7f
#define NTHREADS 256

// anchors / stride, exact binary fractions
__device__ __constant__ float d_anch[3][3][2] = {
    {{10.f/8.f,  13.f/8.f},  {16.f/8.f,  30.f/8.f},  {33.f/8.f,  23.f/8.f}},
    {{30.f/16.f, 61.f/16.f}, {62.f/16.f, 45.f/16.f}, {59.f/16.f, 119.f/16.f}},
    {{116.f/32.f,90.f/32.f}, {156.f/32.f,198.f/32.f},{373.f/32.f,326.f/32.f}},
};

__device__ __forceinline__ float bcef(float x, float t) {
    return fmaxf(x, 0.0f) - x * t + log1pf(expf(-fabsf(x)));
}
__device__ __forceinline__ float sigm(float x) {
    return 1.0f / (1.0f + expf(-x));
}

// ---------------------------------------------------------------------------
// Kernel 2: per-(offset,anchor,target) entries. grid = 3 * bpl blocks.
// Writes per-block partials {lbox_sum, cnt, lcls_sum} and atomicMax into tobj.
// ---------------------------------------------------------------------------
__global__ void per_target_kernel(const float* __restrict__ pred0,
                                  const float* __restrict__ pred1,
                                  const float* __restrict__ pred2,
                                  const float* __restrict__ targets,
                                  int nt, int bpl,
                                  float* __restrict__ ws,       // tobj base
                                  float* __restrict__ tgtpart,  // 3*bpl*3 floats
                                  int n0, int n1)
{
    int layer = blockIdx.x / bpl;
    int sub   = blockIdx.x % bpl;
    const float* pred; float* tobj; int H, W;
    if (layer == 0)      { pred = pred0; tobj = ws;           H = 80; W = 80; }
    else if (layer == 1) { pred = pred1; tobj = ws + n0;      H = 40; W = 40; }
    else                 { pred = pred2; tobj = ws + n0 + n1; H = 20; W = 20; }

    int j = sub * blockDim.x + threadIdx.x;
    int total = 15 * nt;

    float lbox = 0.0f, cnt = 0.0f, lcls = 0.0f;

    if (j < total) {
        int t = j % nt;
        int a = (j / nt) % 3;
        int o = j / (nt * 3);

        const float* tg = targets + t * 6;
        float tb = tg[0], tc = tg[1];
        float gx = tg[2] * (float)W, gy = tg[3] * (float)H;
        float gw = tg[4] * (float)W, gh = tg[5] * (float)H;

        float aw = d_anch[layer][a][0], ah = d_anch[layer][a][1];
        float rw = gw / (aw + 1e-16f), rh = gh / (ah + 1e-16f);
        float rmax = fmaxf(fmaxf(rw, 1.0f / rw), fmaxf(rh, 1.0f / rh));
        bool aok = rmax < 4.0f;

        float fxi = floorf(gx), fyi = floorf(gy);
        float fx = gx - fxi, fy = gy - fyi;
        bool selo;
        switch (o) {
            case 0: selo = true; break;
            case 1: selo = (fx > 0.5f) && (fxi < (float)(W - 1)); break;
            case 2: selo = (fy > 0.5f) && (fyi < (float)(H - 1)); break;
            case 3: selo = (fx < 0.5f) && (fxi > 0.0f); break;
            default: selo = (fy < 0.5f) && (fyi > 0.0f); break;
        }

        if (aok && selo) {
            const float offx[5] = {0.f, 1.f, 0.f, -1.f, 0.f};
            const float offy[5] = {0.f, 0.f, 1.f, 0.f, -1.f};
            float gex = gx - offx[o], gey = gy - offy[o];
            int gix = min(max((int)floorf(gex), 0), W - 1);
            int giy = min(max((int)floorf(gey), 0), H - 1);
            float txc = gex - (float)gix, tyc = gey - (float)giy;
            // target box
            float tx1 = txc - gw * 0.5f, ty1 = tyc - gh * 0.5f;
            float tx2 = txc + gw * 0.5f, ty2 = tyc + gh * 0.5f;

            int b = (int)tb, cls = (int)tc;
            size_t cell = ((((size_t)b * 3 + a) * H + giy) * W + gix);
            const float* pm = pred + cell * 85;

            float pxc = sigm(pm[0]) * 2.0f - 0.5f;
            float pyc = sigm(pm[1]) * 2.0f - 0.5f;
            float sw = sigm(pm[2]) * 2.0f;
            float sh = sigm(pm[3]) * 2.0f;
            float pw = sw * sw * aw, ph = sh * sh * ah;
            float px1 = pxc - pw * 0.5f, py1 = pyc - ph * 0.5f;
            float px2 = pxc + pw * 0.5f, py2 = pyc + ph * 0.5f;

            // CIoU(pbox, tbox)
            float ix1 = fmaxf(px1, tx1), iy1 = fmaxf(py1, ty1);
            float ix2 = fminf(px2, tx2), iy2 = fminf(py2, ty2);
            float inter = fmaxf(ix2 - ix1, 0.0f) * fmaxf(iy2 - iy1, 0.0f);
            float a1 = (px2 - px1) * (py2 - py1);
            float a2 = (tx2 - tx1) * (ty2 - ty1);
            float uni = a1 + a2 - inter + EPSF;
            float iou = inter / uni;
            float ex1 = fminf(px1, tx1), ey1 = fminf(py1, ty1);
            float ex2 = fmaxf(px2, tx2), ey2 = fmaxf(py2, ty2);
            float cw = ex2 - ex1, chh = ey2 - ey1;
            float c2 = cw * cw + chh * chh + EPSF;
            float dx = px1 + px2 - tx1 - tx2;
            float dy = py1 + py2 - ty1 - ty2;
            float rho2 = (dx * dx + dy * dy) * 0.25f;
            float w1 = px2 - px1, h1 = py2 - py1;
            float w2 = tx2 - tx1, h2 = ty2 - ty1;
            float dat = atanf(w2 / (h2 + EPSF)) - atanf(w1 / (h1 + EPSF));
            float v = 0.40528473f * dat * dat;   // 4/pi^2
            float alpha = v / (1.0f - iou + v + EPSF);
            float ciou = iou - rho2 / c2 - alpha * v;

            lbox = 1.0f - ciou;
            cnt = 1.0f;

            float vobj = fmaxf(ciou, 0.0f);
            if (vobj > 0.0f)
                atomicMax((unsigned int*)&tobj[cell], __float_as_uint(vobj));

            float s = 0.0f;
            for (int c = 0; c < 80; ++c) {
                float x = pm[5 + c];
                float tt = (c == cls) ? 1.0f : 0.0f;
                s += bcef(x, tt);
            }
            lcls = s;
        }
    }

    // deterministic block tree-reduce of (lbox, cnt, lcls)
    __shared__ float sA[NTHREADS], sB[NTHREADS], sC[NTHREADS];
    sA[threadIdx.x] = lbox; sB[threadIdx.x] = cnt; sC[threadIdx.x] = lcls;
    __syncthreads();
    for (int st = NTHREADS / 2; st > 0; st >>= 1) {
        if (threadIdx.x < st) {
            sA[threadIdx.x] += sA[threadIdx.x + st];
            sB[threadIdx.x] += sB[threadIdx.x + st];
            sC[threadIdx.x] += sC[threadIdx.x + st];
        }
        __syncthreads();
    }
    if (threadIdx.x == 0) {
        float* p = tgtpart + (size_t)blockIdx.x * 3;
        p[0] = sA[0]; p[1] = sB[0]; p[2] = sC[0];
    }
}

// ---------------------------------------------------------------------------
// Kernel 3: objectness BCE over every grid cell, weighted balance/N_layer.
// ---------------------------------------------------------------------------
__global__ void obj_kernel(const float* __restrict__ pred0,
                           const float* __restrict__ pred1,
                           const float* __restrict__ pred2,
                           const float* __restrict__ tobj_base,
                           int n0, int n1, int n2,
                           float* __restrict__ objpart)
{
    int idx = blockIdx.x * blockDim.x + threadIdx.x;
    int N = n0 + n1 + n2;
    float acc = 0.0f;
    if (idx < N) {
        const float* pred; const float* tobj; int cell; float w;
        if (idx < n0)           { pred = pred0; tobj = tobj_base;           cell = idx;            w = 4.0f / (float)n0; }
        else if (idx < n0 + n1) { pred = pred1; tobj = tobj_base + n0;      cell = idx - n0;       w = 1.0f / (float)n1; }
        else                    { pred = pred2; tobj = tobj_base + n0 + n1; cell = idx - n0 - n1;  w = 0.4f / (float)n2; }
        float x = pred[(size_t)cell * 85 + 4];
        float t = tobj[cell];
        acc = w * bcef(x, t);
    }
    __shared__ float s[NTHREADS];
    s[threadIdx.x] = acc;
    __syncthreads();
    for (int st = NTHREADS / 2; st > 0; st >>= 1) {
        if (threadIdx.x < st) s[threadIdx.x] += s[threadIdx.x + st];
        __syncthreads();
    }
    if (threadIdx.x == 0) objpart[blockIdx.x] = s[0];
}

// ---------------------------------------------------------------------------
// Kernel 4: final deterministic combine.
// ---------------------------------------------------------------------------
__global__ void final_kernel(const float* __restrict__ objpart, int nb_obj,
                             const float* __restrict__ tgtpart, int bpl,
                             float* __restrict__ out, int B)
{
    __shared__ float s[NTHREADS];
    float acc = 0.0f;
    for (int i = threadIdx.x; i < nb_obj; i += blockDim.x) acc += objpart[i];
    s[threadIdx.x] = acc;
    __syncthreads();
    for (int st = NTHREADS / 2; st > 0; st >>= 1) {
        if (threadIdx.x < st) s[threadIdx.x] += s[threadIdx.x + st];
        __syncthreads();
    }
    if (threadIdx.x == 0) {
        float lobj = s[0];
        float lb = 0.0f, lc = 0.0f;
        for (int layer = 0; layer < 3; ++layer) {
            float sb = 0.0f, scnt = 0.0f, sl = 0.0f;
            for (int k = 0; k < bpl; ++k) {
                const float* p = tgtpart + (size_t)(layer * bpl + k) * 3;
                sb += p[0]; scnt += p[1]; sl += p[2];
            }
            if (scnt > 0.0f) {
                lb += sb / fmaxf(scnt, 1.0f);
                lc += sl / fmaxf(scnt * 80.0f, 1.0f);
            }
        }
        out[0] = (0.05f * lb + lobj + 0.5f * lc) * (float)B;
    }
}

extern "C" void kernel_launch(void* const* d_in, const int* in_sizes, int n_in,
                              void* d_out, int out_size, void* d_ws, size_t ws_size,
                              hipStream_t stream) {
    const float* pred0 = (const float*)d_in[0];
    const float* pred1 = (const float*)d_in[1];
    const float* pred2 = (const float*)d_in[2];
    const float* targets = (const float*)d_in[3];

    int B = in_sizes[0] / (3 * 80 * 80 * 85);
    int nt = in_sizes[3] / 6;
    int n0 = B * 3 * 80 * 80;
    int n1 = B * 3 * 40 * 40;
    int n2 = B * 3 * 20 * 20;
    int tobjTotal = n0 + n1 + n2;
    int NB = (tobjTotal + NTHREADS - 1) / NTHREADS;
    int bpl = (15 * nt + NTHREADS - 1) / NTHREADS;

    float* ws = (float*)d_ws;
    float* objpart = ws + tobjTotal;
    float* tgtpart = objpart + NB;
    size_t needed = (size_t)(tobjTotal + NB + 3 * bpl * 3) * sizeof(float);

    hipMemsetAsync(d_ws, 0, needed, stream);
    per_target_kernel<<<3 * bpl, NTHREADS, 0, stream>>>(
        pred0, pred1, pred2, targets, nt, bpl, ws, tgtpart, n0, n1);
    obj_kernel<<<NB, NTHREADS, 0, stream>>>(
        pred0, pred1, pred2, ws, n0, n1, n2, objpart);
    final_kernel<<<1, NTHREADS, 0, stream>>>(
        objpart, NB, tgtpart, bpl, (float*)d_out, B);
}

// Round 2
// 44.413 us; speedup vs baseline: 1.6755x; 1.6755x over previous
//
#include <hip/hip_runtime.h>
#include <math.h>

#define EPSF 1e-7f
#define NTHREADS 256

// anchors / stride, exact binary fractions
__device__ __constant__ float d_anch[3][3][2] = {
    {{10.f/8.f,  13.f/8.f},  {16.f/8.f,  30.f/8.f},  {33.f/8.f,  23.f/8.f}},
    {{30.f/16.f, 61.f/16.f}, {62.f/16.f, 45.f/16.f}, {59.f/16.f, 119.f/16.f}},
    {{116.f/32.f,90.f/32.f}, {156.f/32.f,198.f/32.f},{373.f/32.f,326.f/32.f}},
};

__device__ __forceinline__ float bcef(float x, float t) {
    return fmaxf(x, 0.0f) - x * t + log1pf(expf(-fabsf(x)));
}
__device__ __forceinline__ float sigm(float x) {
    return 1.0f / (1.0f + expf(-x));
}

__device__ __forceinline__ float block_reduce(float v, float* s) {
    s[threadIdx.x] = v;
    __syncthreads();
    for (int st = NTHREADS / 2; st > 0; st >>= 1) {
        if (threadIdx.x < st) s[threadIdx.x] += s[threadIdx.x + st];
        __syncthreads();
    }
    float r = s[0];
    __syncthreads();
    return r;
}

// ---------------------------------------------------------------------------
// Kernel A: per-(offset,anchor,target) entries. grid = 3*bpl blocks.
// CIoU + lbox/cnt partials + tobj atomicMax + meta {cell, cls} for cls kernel.
// ---------------------------------------------------------------------------
__global__ void per_target_kernel(const float* __restrict__ pred0,
                                  const float* __restrict__ pred1,
                                  const float* __restrict__ pred2,
                                  const float* __restrict__ targets,
                                  int nt, int bpl,
                                  float* __restrict__ tobj_base,
                                  float* __restrict__ tgtpart,  // 3*bpl*2 floats
                                  int2* __restrict__ meta,      // 3*15*nt entries
                                  int n0, int n1)
{
    int layer = blockIdx.x / bpl;
    int sub   = blockIdx.x % bpl;
    const float* pred; float* tobj; int H, W;
    if (layer == 0)      { pred = pred0; tobj = tobj_base;           H = 80; W = 80; }
    else if (layer == 1) { pred = pred1; tobj = tobj_base + n0;      H = 40; W = 40; }
    else                 { pred = pred2; tobj = tobj_base + n0 + n1; H = 20; W = 20; }

    int j = sub * blockDim.x + threadIdx.x;
    int total = 15 * nt;

    float lbox = 0.0f, cnt = 0.0f;
    int2 mout = make_int2(-1, 0);

    if (j < total) {
        int t = j % nt;
        int a = (j / nt) % 3;
        int o = j / (nt * 3);

        const float* tg = targets + t * 6;
        float tb = tg[0], tc = tg[1];
        float gx = tg[2] * (float)W, gy = tg[3] * (float)H;
        float gw = tg[4] * (float)W, gh = tg[5] * (float)H;

        float aw = d_anch[layer][a][0], ah = d_anch[layer][a][1];
        float rw = gw / (aw + 1e-16f), rh = gh / (ah + 1e-16f);
        float rmax = fmaxf(fmaxf(rw, 1.0f / rw), fmaxf(rh, 1.0f / rh));
        bool aok = rmax < 4.0f;

        float fxi = floorf(gx), fyi = floorf(gy);
        float fx = gx - fxi, fy = gy - fyi;
        bool selo;
        switch (o) {
            case 0: selo = true; break;
            case 1: selo = (fx > 0.5f) && (fxi < (float)(W - 1)); break;
            case 2: selo = (fy > 0.5f) && (fyi < (float)(H - 1)); break;
            case 3: selo = (fx < 0.5f) && (fxi > 0.0f); break;
            default: selo = (fy < 0.5f) && (fyi > 0.0f); break;
        }

        if (aok && selo) {
            // branchless offsets (no scratch array)
            float ox = (o == 1) ? 1.0f : (o == 3) ? -1.0f : 0.0f;
            float oy = (o == 2) ? 1.0f : (o == 4) ? -1.0f : 0.0f;
            float gex = gx - ox, gey = gy - oy;
            int gix = min(max((int)floorf(gex), 0), W - 1);
            int giy = min(max((int)floorf(gey), 0), H - 1);
            float txc = gex - (float)gix, tyc = gey - (float)giy;
            float tx1 = txc - gw * 0.5f, ty1 = tyc - gh * 0.5f;
            float tx2 = txc + gw * 0.5f, ty2 = tyc + gh * 0.5f;

            int b = (int)tb, cls = (int)tc;
            int cell = (int)(((((size_t)b * 3 + a) * H + giy) * W + gix));
            const float* pm = pred + (size_t)cell * 85;

            float p0 = pm[0], p1v = pm[1], p2v = pm[2], p3 = pm[3];
            float pxc = sigm(p0) * 2.0f - 0.5f;
            float pyc = sigm(p1v) * 2.0f - 0.5f;
            float sw = sigm(p2v) * 2.0f;
            float sh = sigm(p3) * 2.0f;
            float pw = sw * sw * aw, ph = sh * sh * ah;
            float px1 = pxc - pw * 0.5f, py1 = pyc - ph * 0.5f;
            float px2 = pxc + pw * 0.5f, py2 = pyc + ph * 0.5f;

            // CIoU(pbox, tbox)
            float ix1 = fmaxf(px1, tx1), iy1 = fmaxf(py1, ty1);
            float ix2 = fminf(px2, tx2), iy2 = fminf(py2, ty2);
            float inter = fmaxf(ix2 - ix1, 0.0f) * fmaxf(iy2 - iy1, 0.0f);
            float a1 = (px2 - px1) * (py2 - py1);
            float a2 = (tx2 - tx1) * (ty2 - ty1);
            float uni = a1 + a2 - inter + EPSF;
            float iou = inter / uni;
            float ex1 = fminf(px1, tx1), ey1 = fminf(py1, ty1);
            float ex2 = fmaxf(px2, tx2), ey2 = fmaxf(py2, ty2);
            float cw = ex2 - ex1, chh = ey2 - ey1;
            float c2 = cw * cw + chh * chh + EPSF;
            float dx = px1 + px2 - tx1 - tx2;
            float dy = py1 + py2 - ty1 - ty2;
            float rho2 = (dx * dx + dy * dy) * 0.25f;
            float w1 = px2 - px1, h1 = py2 - py1;
            float w2 = tx2 - tx1, h2 = ty2 - ty1;
            float dat = atanf(w2 / (h2 + EPSF)) - atanf(w1 / (h1 + EPSF));
            float v = 0.40528473f * dat * dat;   // 4/pi^2
            float alpha = v / (1.0f - iou + v + EPSF);
            float ciou = iou - rho2 / c2 - alpha * v;

            lbox = 1.0f - ciou;
            cnt = 1.0f;
            mout = make_int2(cell, cls);

            float vobj = fmaxf(ciou, 0.0f);
            if (vobj > 0.0f)
                atomicMax((unsigned int*)&tobj[cell], __float_as_uint(vobj));
        }
        meta[layer * total + j] = mout;
    }

    __shared__ float s[NTHREADS];
    float rb = block_reduce(lbox, s);
    float rc = block_reduce(cnt, s);
    if (threadIdx.x == 0) {
        tgtpart[(size_t)blockIdx.x * 2 + 0] = rb;
        tgtpart[(size_t)blockIdx.x * 2 + 1] = rc;
    }
}

// ---------------------------------------------------------------------------
// Kernel B: class BCE — one 64-lane wave per entry, coalesced class reads.
// grid = 3 * bpl2 blocks (4 entries per block).
// ---------------------------------------------------------------------------
__global__ void cls_kernel(const float* __restrict__ pred0,
                           const float* __restrict__ pred1,
                           const float* __restrict__ pred2,
                           const int2* __restrict__ meta,
                           int perLayer, int bpl2,
                           float* __restrict__ clspart)
{
    int layer = blockIdx.x / bpl2;
    int sub   = blockIdx.x % bpl2;
    int wid   = threadIdx.x >> 6;
    int lane  = threadIdx.x & 63;
    int eL    = sub * 4 + wid;

    float acc = 0.0f;
    if (eL < perLayer) {
        int2 m = meta[(size_t)layer * perLayer + eL];
        if (m.x >= 0) {
            const float* pred = (layer == 0) ? pred0 : (layer == 1) ? pred1 : pred2;
            const float* pm = pred + (size_t)m.x * 85 + 5;
            float x0 = pm[lane];
            acc = bcef(x0, (lane == m.y) ? 1.0f : 0.0f);
            if (lane < 16) {
                float x1 = pm[64 + lane];
                acc += bcef(x1, ((64 + lane) == m.y) ? 1.0f : 0.0f);
            }
        }
    }
    __shared__ float s[NTHREADS];
    float r = block_reduce(acc, s);
    if (threadIdx.x == 0) clspart[blockIdx.x] = r;
}

// ---------------------------------------------------------------------------
// Kernel C: objectness BCE over every grid cell, weighted balance/N_layer.
// ---------------------------------------------------------------------------
__global__ void obj_kernel(const float* __restrict__ pred0,
                           const float* __restrict__ pred1,
                           const float* __restrict__ pred2,
                           const float* __restrict__ tobj_base,
                           int n0, int n1, int n2,
                           float* __restrict__ objpart)
{
    int idx = blockIdx.x * blockDim.x + threadIdx.x;
    int N = n0 + n1 + n2;
    float acc = 0.0f;
    if (idx < N) {
        const float* pred; const float* tobj; int cell; float w;
        if (idx < n0)           { pred = pred0; tobj = tobj_base;           cell = idx;            w = 4.0f / (float)n0; }
        else if (idx < n0 + n1) { pred = pred1; tobj = tobj_base + n0;      cell = idx - n0;       w = 1.0f / (float)n1; }
        else                    { pred = pred2; tobj = tobj_base + n0 + n1; cell = idx - n0 - n1;  w = 0.4f / (float)n2; }
        float x = pred[(size_t)cell * 85 + 4];
        float t = tobj[cell];
        acc = w * bcef(x, t);
    }
    __shared__ float s[NTHREADS];
    float r = block_reduce(acc, s);
    if (threadIdx.x == 0) objpart[blockIdx.x] = r;
}

// ---------------------------------------------------------------------------
// Kernel D: final deterministic combine.
// ---------------------------------------------------------------------------
__global__ void final_kernel(const float* __restrict__ objpart, int nb_obj,
                             const float* __restrict__ tgtpart, int bpl,
                             const float* __restrict__ clspart, int bpl2,
                             float* __restrict__ out, int B)
{
    __shared__ float s[NTHREADS];
    int tid = threadIdx.x;

    float v = 0.0f;
    for (int i = tid; i < nb_obj; i += NTHREADS) v += objpart[i];
    float lobj = block_reduce(v, s);

    float r_lb[3], r_cnt[3], r_cls[3];
    for (int L = 0; L < 3; ++L) {
        v = 0.0f;
        for (int i = tid; i < bpl; i += NTHREADS) v += tgtpart[(size_t)(L * bpl + i) * 2 + 0];
        r_lb[L] = block_reduce(v, s);
        v = 0.0f;
        for (int i = tid; i < bpl; i += NTHREADS) v += tgtpart[(size_t)(L * bpl + i) * 2 + 1];
        r_cnt[L] = block_reduce(v, s);
        v = 0.0f;
        for (int i = tid; i < bpl2; i += NTHREADS) v += clspart[L * bpl2 + i];
        r_cls[L] = block_reduce(v, s);
    }

    if (tid == 0) {
        float lb = 0.0f, lc = 0.0f;
        for (int L = 0; L < 3; ++L) {
            if (r_cnt[L] > 0.0f) {
                lb += r_lb[L] / fmaxf(r_cnt[L], 1.0f);
                lc += r_cls[L] / fmaxf(r_cnt[L] * 80.0f, 1.0f);
            }
        }
        out[0] = (0.05f * lb + lobj + 0.5f * lc) * (float)B;
    }
}

extern "C" void kernel_launch(void* const* d_in, const int* in_sizes, int n_in,
                              void* d_out, int out_size, void* d_ws, size_t ws_size,
                              hipStream_t stream) {
    const float* pred0 = (const float*)d_in[0];
    const float* pred1 = (const float*)d_in[1];
    const float* pred2 = (const float*)d_in[2];
    const float* targets = (const float*)d_in[3];

    int B = in_sizes[0] / (3 * 80 * 80 * 85);
    int nt = in_sizes[3] / 6;
    int n0 = B * 3 * 80 * 80;
    int n1 = B * 3 * 40 * 40;
    int n2 = B * 3 * 20 * 20;
    int tobjTotal = n0 + n1 + n2;
    int NB = (tobjTotal + NTHREADS - 1) / NTHREADS;
    int perLayer = 15 * nt;
    int bpl = (perLayer + NTHREADS - 1) / NTHREADS;
    int bpl2 = (perLayer + 3) / 4;

    // workspace layout (meta first: int2, 8B-aligned at base)
    int2* meta = (int2*)d_ws;
    float* tobj = (float*)d_ws + (size_t)2 * 3 * perLayer;
    float* objpart = tobj + tobjTotal;
    float* tgtpart = objpart + NB;
    float* clspart = tgtpart + (size_t)3 * bpl * 2;

    // only tobj needs zeroing; everything else is fully overwritten each call
    hipMemsetAsync(tobj, 0, (size_t)tobjTotal * sizeof(float), stream);

    per_target_kernel<<<3 * bpl, NTHREADS, 0, stream>>>(
        pred0, pred1, pred2, targets, nt, bpl, tobj, tgtpart, meta, n0, n1);
    cls_kernel<<<3 * bpl2, NTHREADS, 0, stream>>>(
        pred0, pred1, pred2, meta, perLayer, bpl2, clspart);
    obj_kernel<<<NB, NTHREADS, 0, stream>>>(
        pred0, pred1, pred2, tobj, n0, n1, n2, objpart);
    final_kernel<<<1, NTHREADS, 0, stream>>>(
        objpart, NB, tgtpart, bpl, clspart, bpl2, (float*)d_out, B);
}

// Round 3
// 43.834 us; speedup vs baseline: 1.6976x; 1.0132x over previous
//
#include <hip/hip_runtime.h>
#include <math.h>

#define EPSF 1e-7f
#define NTHREADS 256

// anchors / stride, exact binary fractions
__device__ __constant__ float d_anch[3][3][2] = {
    {{10.f/8.f,  13.f/8.f},  {16.f/8.f,  30.f/8.f},  {33.f/8.f,  23.f/8.f}},
    {{30.f/16.f, 61.f/16.f}, {62.f/16.f, 45.f/16.f}, {59.f/16.f, 119.f/16.f}},
    {{116.f/32.f,90.f/32.f}, {156.f/32.f,198.f/32.f},{373.f/32.f,326.f/32.f}},
};

__device__ __forceinline__ float bcef(float x, float t) {
    return fmaxf(x, 0.0f) - x * t + log1pf(expf(-fabsf(x)));
}
__device__ __forceinline__ float sigm(float x) {
    return 1.0f / (1.0f + expf(-x));
}

__device__ __forceinline__ float block_reduce(float v, float* s) {
    s[threadIdx.x] = v;
    __syncthreads();
    for (int st = NTHREADS / 2; st > 0; st >>= 1) {
        if (threadIdx.x < st) s[threadIdx.x] += s[threadIdx.x + st];
        __syncthreads();
    }
    float r = s[0];
    __syncthreads();
    return r;
}

// ---------------------------------------------------------------------------
// Kernel Z: fast vectorized zero of tobj (replaces slow rocclr fill path).
// ---------------------------------------------------------------------------
__global__ void zero_tobj_kernel(float4* __restrict__ p, int n4)
{
    int i = blockIdx.x * blockDim.x + threadIdx.x;
    if (i < n4) p[i] = make_float4(0.f, 0.f, 0.f, 0.f);
}

// ---------------------------------------------------------------------------
// Kernel A: per-(offset,anchor,target) entries. grid = 3*bpl blocks.
// CIoU + lbox/cnt partials + tobj atomicMax + meta {cell, cls} for cls kernel.
// ---------------------------------------------------------------------------
__global__ void per_target_kernel(const float* __restrict__ pred0,
                                  const float* __restrict__ pred1,
                                  const float* __restrict__ pred2,
                                  const float* __restrict__ targets,
                                  int nt, int bpl,
                                  float* __restrict__ tobj_base,
                                  float* __restrict__ tgtpart,  // 3*bpl*2 floats
                                  int2* __restrict__ meta,      // 3*15*nt entries
                                  int n0, int n1)
{
    int layer = blockIdx.x / bpl;
    int sub   = blockIdx.x % bpl;
    const float* pred; float* tobj; int H, W;
    if (layer == 0)      { pred = pred0; tobj = tobj_base;           H = 80; W = 80; }
    else if (layer == 1) { pred = pred1; tobj = tobj_base + n0;      H = 40; W = 40; }
    else                 { pred = pred2; tobj = tobj_base + n0 + n1; H = 20; W = 20; }

    int j = sub * blockDim.x + threadIdx.x;
    int total = 15 * nt;

    float lbox = 0.0f, cnt = 0.0f;
    int2 mout = make_int2(-1, 0);

    if (j < total) {
        int t = j % nt;
        int a = (j / nt) % 3;
        int o = j / (nt * 3);

        const float* tg = targets + t * 6;
        float tb = tg[0], tc = tg[1];
        float gx = tg[2] * (float)W, gy = tg[3] * (float)H;
        float gw = tg[4] * (float)W, gh = tg[5] * (float)H;

        float aw = d_anch[layer][a][0], ah = d_anch[layer][a][1];
        float rw = gw / (aw + 1e-16f), rh = gh / (ah + 1e-16f);
        float rmax = fmaxf(fmaxf(rw, 1.0f / rw), fmaxf(rh, 1.0f / rh));
        bool aok = rmax < 4.0f;

        float fxi = floorf(gx), fyi = floorf(gy);
        float fx = gx - fxi, fy = gy - fyi;
        bool selo;
        switch (o) {
            case 0: selo = true; break;
            case 1: selo = (fx > 0.5f) && (fxi < (float)(W - 1)); break;
            case 2: selo = (fy > 0.5f) && (fyi < (float)(H - 1)); break;
            case 3: selo = (fx < 0.5f) && (fxi > 0.0f); break;
            default: selo = (fy < 0.5f) && (fyi > 0.0f); break;
        }

        if (aok && selo) {
            float ox = (o == 1) ? 1.0f : (o == 3) ? -1.0f : 0.0f;
            float oy = (o == 2) ? 1.0f : (o == 4) ? -1.0f : 0.0f;
            float gex = gx - ox, gey = gy - oy;
            int gix = min(max((int)floorf(gex), 0), W - 1);
            int giy = min(max((int)floorf(gey), 0), H - 1);
            float txc = gex - (float)gix, tyc = gey - (float)giy;
            float tx1 = txc - gw * 0.5f, ty1 = tyc - gh * 0.5f;
            float tx2 = txc + gw * 0.5f, ty2 = tyc + gh * 0.5f;

            int b = (int)tb, cls = (int)tc;
            int cell = (int)(((((size_t)b * 3 + a) * H + giy) * W + gix));
            const float* pm = pred + (size_t)cell * 85;

            float p0 = pm[0], p1v = pm[1], p2v = pm[2], p3 = pm[3];
            float pxc = sigm(p0) * 2.0f - 0.5f;
            float pyc = sigm(p1v) * 2.0f - 0.5f;
            float sw = sigm(p2v) * 2.0f;
            float sh = sigm(p3) * 2.0f;
            float pw = sw * sw * aw, ph = sh * sh * ah;
            float px1 = pxc - pw * 0.5f, py1 = pyc - ph * 0.5f;
            float px2 = pxc + pw * 0.5f, py2 = pyc + ph * 0.5f;

            // CIoU(pbox, tbox)
            float ix1 = fmaxf(px1, tx1), iy1 = fmaxf(py1, ty1);
            float ix2 = fminf(px2, tx2), iy2 = fminf(py2, ty2);
            float inter = fmaxf(ix2 - ix1, 0.0f) * fmaxf(iy2 - iy1, 0.0f);
            float a1 = (px2 - px1) * (py2 - py1);
            float a2 = (tx2 - tx1) * (ty2 - ty1);
            float uni = a1 + a2 - inter + EPSF;
            float iou = inter / uni;
            float ex1 = fminf(px1, tx1), ey1 = fminf(py1, ty1);
            float ex2 = fmaxf(px2, tx2), ey2 = fmaxf(py2, ty2);
            float cw = ex2 - ex1, chh = ey2 - ey1;
            float c2 = cw * cw + chh * chh + EPSF;
            float dx = px1 + px2 - tx1 - tx2;
            float dy = py1 + py2 - ty1 - ty2;
            float rho2 = (dx * dx + dy * dy) * 0.25f;
            float w1 = px2 - px1, h1 = py2 - py1;
            float w2 = tx2 - tx1, h2 = ty2 - ty1;
            float dat = atanf(w2 / (h2 + EPSF)) - atanf(w1 / (h1 + EPSF));
            float v = 0.40528473f * dat * dat;   // 4/pi^2
            float alpha = v / (1.0f - iou + v + EPSF);
            float ciou = iou - rho2 / c2 - alpha * v;

            lbox = 1.0f - ciou;
            cnt = 1.0f;
            mout = make_int2(cell, cls);

            float vobj = fmaxf(ciou, 0.0f);
            if (vobj > 0.0f)
                atomicMax((unsigned int*)&tobj[cell], __float_as_uint(vobj));
        }
        meta[layer * total + j] = mout;
    }

    __shared__ float s[NTHREADS];
    float rb = block_reduce(lbox, s);
    float rc = block_reduce(cnt, s);
    if (threadIdx.x == 0) {
        tgtpart[(size_t)blockIdx.x * 2 + 0] = rb;
        tgtpart[(size_t)blockIdx.x * 2 + 1] = rc;
    }
}

// ---------------------------------------------------------------------------
// Kernel B: class BCE — one 64-lane wave per entry, coalesced class reads.
// ---------------------------------------------------------------------------
__global__ void cls_kernel(const float* __restrict__ pred0,
                           const float* __restrict__ pred1,
                           const float* __restrict__ pred2,
                           const int2* __restrict__ meta,
                           int perLayer, int bpl2,
                           float* __restrict__ clspart)
{
    int layer = blockIdx.x / bpl2;
    int sub   = blockIdx.x % bpl2;
    int wid   = threadIdx.x >> 6;
    int lane  = threadIdx.x & 63;
    int eL    = sub * 4 + wid;

    float acc = 0.0f;
    if (eL < perLayer) {
        int2 m = meta[(size_t)layer * perLayer + eL];
        if (m.x >= 0) {
            const float* pred = (layer == 0) ? pred0 : (layer == 1) ? pred1 : pred2;
            const float* pm = pred + (size_t)m.x * 85 + 5;
            float x0 = pm[lane];
            acc = bcef(x0, (lane == m.y) ? 1.0f : 0.0f);
            if (lane < 16) {
                float x1 = pm[64 + lane];
                acc += bcef(x1, ((64 + lane) == m.y) ? 1.0f : 0.0f);
            }
        }
    }
    __shared__ float s[NTHREADS];
    float r = block_reduce(acc, s);
    if (threadIdx.x == 0) clspart[blockIdx.x] = r;
}

// ---------------------------------------------------------------------------
// Kernel C: objectness BCE over every grid cell, weighted balance/N_layer.
// ---------------------------------------------------------------------------
__global__ void obj_kernel(const float* __restrict__ pred0,
                           const float* __restrict__ pred1,
                           const float* __restrict__ pred2,
                           const float* __restrict__ tobj_base,
                           int n0, int n1, int n2,
                           float* __restrict__ objpart)
{
    int idx = blockIdx.x * blockDim.x + threadIdx.x;
    int N = n0 + n1 + n2;
    float acc = 0.0f;
    if (idx < N) {
        const float* pred; const float* tobj; int cell; float w;
        if (idx < n0)           { pred = pred0; tobj = tobj_base;           cell = idx;            w = 4.0f / (float)n0; }
        else if (idx < n0 + n1) { pred = pred1; tobj = tobj_base + n0;      cell = idx - n0;       w = 1.0f / (float)n1; }
        else                    { pred = pred2; tobj = tobj_base + n0 + n1; cell = idx - n0 - n1;  w = 0.4f / (float)n2; }
        float x = pred[(size_t)cell * 85 + 4];
        float t = tobj[cell];
        acc = w * bcef(x, t);
    }
    __shared__ float s[NTHREADS];
    float r = block_reduce(acc, s);
    if (threadIdx.x == 0) objpart[blockIdx.x] = r;
}

// ---------------------------------------------------------------------------
// Kernel D: final deterministic combine.
// ---------------------------------------------------------------------------
__global__ void final_kernel(const float* __restrict__ objpart, int nb_obj,
                             const float* __restrict__ tgtpart, int bpl,
                             const float* __restrict__ clspart, int bpl2,
                             float* __restrict__ out, int B)
{
    __shared__ float s[NTHREADS];
    int tid = threadIdx.x;

    float v = 0.0f;
    for (int i = tid; i < nb_obj; i += NTHREADS) v += objpart[i];
    float lobj = block_reduce(v, s);

    float r_lb[3], r_cnt[3], r_cls[3];
    for (int L = 0; L < 3; ++L) {
        v = 0.0f;
        for (int i = tid; i < bpl; i += NTHREADS) v += tgtpart[(size_t)(L * bpl + i) * 2 + 0];
        r_lb[L] = block_reduce(v, s);
        v = 0.0f;
        for (int i = tid; i < bpl; i += NTHREADS) v += tgtpart[(size_t)(L * bpl + i) * 2 + 1];
        r_cnt[L] = block_reduce(v, s);
        v = 0.0f;
        for (int i = tid; i < bpl2; i += NTHREADS) v += clspart[L * bpl2 + i];
        r_cls[L] = block_reduce(v, s);
    }

    if (tid == 0) {
        float lb = 0.0f, lc = 0.0f;
        for (int L = 0; L < 3; ++L) {
            if (r_cnt[L] > 0.0f) {
                lb += r_lb[L] / fmaxf(r_cnt[L], 1.0f);
                lc += r_cls[L] / fmaxf(r_cnt[L] * 80.0f, 1.0f);
            }
        }
        out[0] = (0.05f * lb + lobj + 0.5f * lc) * (float)B;
    }
}

extern "C" void kernel_launch(void* const* d_in, const int* in_sizes, int n_in,
                              void* d_out, int out_size, void* d_ws, size_t ws_size,
                              hipStream_t stream) {
    const float* pred0 = (const float*)d_in[0];
    const float* pred1 = (const float*)d_in[1];
    const float* pred2 = (const float*)d_in[2];
    const float* targets = (const float*)d_in[3];

    int B = in_sizes[0] / (3 * 80 * 80 * 85);
    int nt = in_sizes[3] / 6;
    int n0 = B * 3 * 80 * 80;
    int n1 = B * 3 * 40 * 40;
    int n2 = B * 3 * 20 * 20;
    int tobjTotal = n0 + n1 + n2;
    int NB = (tobjTotal + NTHREADS - 1) / NTHREADS;
    int perLayer = 15 * nt;
    int bpl = (perLayer + NTHREADS - 1) / NTHREADS;
    int bpl2 = (perLayer + 3) / 4;

    // workspace layout (meta first: int2, 8B-aligned at base; tobj 16B-aligned)
    int2* meta = (int2*)d_ws;
    size_t metaFloats = (size_t)2 * 3 * perLayer;
    metaFloats = (metaFloats + 3) & ~(size_t)3;          // 16B-align tobj
    float* tobj = (float*)d_ws + metaFloats;
    float* objpart = tobj + tobjTotal;
    float* tgtpart = objpart + NB;
    float* clspart = tgtpart + (size_t)3 * bpl * 2;

    int n4 = tobjTotal / 4;  // tobjTotal = 403200, divisible by 4
    zero_tobj_kernel<<<(n4 + NTHREADS - 1) / NTHREADS, NTHREADS, 0, stream>>>(
        (float4*)tobj, n4);
    per_target_kernel<<<3 * bpl, NTHREADS, 0, stream>>>(
        pred0, pred1, pred2, targets, nt, bpl, tobj, tgtpart, meta, n0, n1);
    cls_kernel<<<3 * bpl2, NTHREADS, 0, stream>>>(
        pred0, pred1, pred2, meta, perLayer, bpl2, clspart);
    obj_kernel<<<NB, NTHREADS, 0, stream>>>(
        pred0, pred1, pred2, tobj, n0, n1, n2, objpart);
    final_kernel<<<1, NTHREADS, 0, stream>>>(
        objpart, NB, tgtpart, bpl, clspart, bpl2, (float*)d_out, B);
}